// Round 1
// baseline (442.320 us; speedup 1.0000x reference)
//
#include <hip/hip_runtime.h>

// Problem constants (from reference setup_inputs):
//   B=32, S1=S2=14, NC=2, DC=16, F=32, I=8
//   rows = B*S1*S2*NC*DC = 200704, each row is an F x I = 32 x 8 tile.
//   de = row % 32 selects the (d,e) weight slice of W_affine / W_t.
#define N_ROWS     200704
#define F_DIM      32
#define I_DIM      8
#define ROW_ELEMS  256                    // F*I
#define C_ELEMS    51380224LL             // N_ROWS * ROW_ELEMS
#define WAVES_PER_BLOCK 4

__global__ __launch_bounds__(256) void mhsa_softmax_kernel(
    const float* __restrict__ U_hat,     // [rows][32]
    const float* __restrict__ W_t,       // [32][32][8]  (de, f, i)
    const float* __restrict__ W_affine,  // [32][32][8]
    float* __restrict__ out)             // [C | U_hat_I], each rows*256
{
    const int wave = threadIdx.x >> 6;
    const int lane = threadIdx.x & 63;
    const int r    = blockIdx.x * WAVES_PER_BLOCK + wave;  // one wave per row
    // lane owns i = lane&7 and f = (lane>>3) + 8*j, j=0..3.
    // In-row flat offset of element (f,i) = f*8 + i = lane + 64*j  -> fully
    // coalesced 256B wave accesses for weights and both outputs.
    const int fg = lane >> 3;
    const int de = r & 31;

    const float* uh   = U_hat    + (long long)r * F_DIM;
    const float* wa   = W_affine + de * ROW_ELEMS;
    const float* wt   = W_t      + de * ROW_ELEMS;
    float*       outC = out      + (long long)r * ROW_ELEMS;
    float*       outU = out + C_ELEMS + (long long)r * ROW_ELEMS;

    float u[4], wav[4], wtv[4], uhi[4];
#pragma unroll
    for (int j = 0; j < 4; ++j) {
        u[j]   = uh[fg + 8 * j];        // 8-way lane-duplicated, L1 broadcast
        wav[j] = wa[64 * j + lane];     // hot in L1/L2 (64KB total weights)
        wtv[j] = wt[64 * j + lane];
    }

    float sq = 0.f;
#pragma unroll
    for (int j = 0; j < 4; ++j) {
        uhi[j] = u[j] * wav[j];
        outU[64 * j + lane] = uhi[j];
        sq = fmaf(uhi[j], uhi[j], sq);
    }
    // reduce over f: lanes sharing i differ in bits 3..5 -> xor 8,16,32
    sq += __shfl_xor(sq, 8);
    sq += __shfl_xor(sq, 16);
    sq += __shfl_xor(sq, 32);
    const float diag = sq * 0.25f;      // / sqrt(dim_capsules=16)

    float a[4];
    float m = -INFINITY;
#pragma unroll
    for (int j = 0; j < 4; ++j) {
        a[j] = diag * wtv[j];
        m = fmaxf(m, a[j]);
    }
    m = fmaxf(m, __shfl_xor(m, 8));
    m = fmaxf(m, __shfl_xor(m, 16));
    m = fmaxf(m, __shfl_xor(m, 32));

    float e[4], s = 0.f;
#pragma unroll
    for (int j = 0; j < 4; ++j) {
        e[j] = __expf(a[j] - m);
        s += e[j];
    }
    s += __shfl_xor(s, 8);
    s += __shfl_xor(s, 16);
    s += __shfl_xor(s, 32);
    const float inv = 1.0f / s;

#pragma unroll
    for (int j = 0; j < 4; ++j) {
        outC[64 * j + lane] = e[j] * inv;
    }
}

extern "C" void kernel_launch(void* const* d_in, const int* in_sizes, int n_in,
                              void* d_out, int out_size, void* d_ws, size_t ws_size,
                              hipStream_t stream) {
    const float* U_hat    = (const float*)d_in[0];
    const float* W_t      = (const float*)d_in[1];
    const float* W_affine = (const float*)d_in[2];
    float* out = (float*)d_out;

    const int grid = N_ROWS / WAVES_PER_BLOCK;  // 50176 blocks of 256 threads
    mhsa_softmax_kernel<<<grid, 256, 0, stream>>>(U_hat, W_t, W_affine, out);
}

// Round 2
// 436.590 us; speedup vs baseline: 1.0131x; 1.0131x over previous
//
#include <hip/hip_runtime.h>

// B=32, S1=S2=14, NC=2, DC=16, F=32, I=8
// rows = 200704, each row an F x I = 32 x 8 tile; de = row & 31 picks the
// (d,e) weight slice. Outputs: [C | U_hat_I], each rows*256 fp32.
#define N_ROWS      200704
#define ROW_ELEMS   256
#define C_ELEMS     51380224LL
#define BLOCKS      2048
#define WAVES_PER_BLOCK 4
#define TOTAL_WAVES (BLOCKS * WAVES_PER_BLOCK)   // 8192; multiple of 32 =>
                                                 // de is CONSTANT per wave.

__global__ __launch_bounds__(256) void mhsa_softmax_kernel(
    const float* __restrict__ U_hat,     // [rows][32]
    const float* __restrict__ W_t,       // [32][32][8]  (de, f, i)
    const float* __restrict__ W_affine,  // [32][32][8]
    float* __restrict__ out)             // [C | U_hat_I]
{
    const int lane = threadIdx.x & 63;
    const int wid  = blockIdx.x * WAVES_PER_BLOCK + (threadIdx.x >> 6);
    // lane owns i = lane&7, f = (lane>>3) + 8j; in-row offset = lane + 64j
    // -> every weight load / output store is a fully-coalesced 256B access.
    const int fg = lane >> 3;
    const int de = wid & 31;             // invariant across the row loop

    const float* wa = W_affine + de * ROW_ELEMS;
    const float* wt = W_t      + de * ROW_ELEMS;

    // Hoisted: weights loaded ONCE per wave (was: per row).
    float wav[4], wtv[4];
#pragma unroll
    for (int j = 0; j < 4; ++j) {
        wav[j] = wa[64 * j + lane];
        wtv[j] = wt[64 * j + lane];
    }
    // Hoisted: per-i max_f of W_t. Valid because diag >= 0 (sum of squares),
    // so max_f(diag*wt) = diag * max_f(wt).
    float wtmax = fmaxf(fmaxf(wtv[0], wtv[1]), fmaxf(wtv[2], wtv[3]));
    wtmax = fmaxf(wtmax, __shfl_xor(wtmax, 8));
    wtmax = fmaxf(wtmax, __shfl_xor(wtmax, 16));
    wtmax = fmaxf(wtmax, __shfl_xor(wtmax, 32));

    for (int r = wid; r < N_ROWS; r += TOTAL_WAVES) {   // ~25 rows per wave
        const float* uh   = U_hat + (long long)r * 32;
        float*       outC = out   + (long long)r * ROW_ELEMS;
        float*       outU = out + C_ELEMS + (long long)r * ROW_ELEMS;

        float u[4], uhi[4];
#pragma unroll
        for (int j = 0; j < 4; ++j) u[j] = uh[fg + 8 * j];

        float sq = 0.f;
#pragma unroll
        for (int j = 0; j < 4; ++j) {
            uhi[j] = u[j] * wav[j];
            outU[64 * j + lane] = uhi[j];
            sq = fmaf(uhi[j], uhi[j], sq);
        }
        sq += __shfl_xor(sq, 8);
        sq += __shfl_xor(sq, 16);
        sq += __shfl_xor(sq, 32);
        const float diag = sq * 0.25f;      // / sqrt(16)
        const float m    = diag * wtmax;    // exact softmax max

        float e[4], s = 0.f;
#pragma unroll
        for (int j = 0; j < 4; ++j) {
            e[j] = __expf(fmaf(diag, wtv[j], -m));
            s += e[j];
        }
        s += __shfl_xor(s, 8);
        s += __shfl_xor(s, 16);
        s += __shfl_xor(s, 32);
        const float inv = __builtin_amdgcn_rcpf(s);  // s in (0,32], safe

#pragma unroll
        for (int j = 0; j < 4; ++j) outC[64 * j + lane] = e[j] * inv;
    }
}

extern "C" void kernel_launch(void* const* d_in, const int* in_sizes, int n_in,
                              void* d_out, int out_size, void* d_ws, size_t ws_size,
                              hipStream_t stream) {
    const float* U_hat    = (const float*)d_in[0];
    const float* W_t      = (const float*)d_in[1];
    const float* W_affine = (const float*)d_in[2];
    float* out = (float*)d_out;

    mhsa_softmax_kernel<<<BLOCKS, 256, 0, stream>>>(U_hat, W_t, W_affine, out);
}